// Round 1
// baseline (573.923 us; speedup 1.0000x reference)
//
#include <hip/hip_runtime.h>

// FlowNetC correlation: B=8, C=128, H=128, W=256, PAD=4, MD=4, K=1, S1=S2=1
// out[b, (dy+4)*9+(dx+4), h, w] = (1/128) * sum_c in1[b,c,h,w]*in2[b,c,h+dy,w+dx]
// (in2 zero outside bounds)

#define NB 8
#define NC 128
#define NH 128
#define NW 256
#define ND 9              // displacements per axis
#define CC 4              // channels per LDS chunk
#define WPAD (NW + 8)     // 264
#define NTH (ND * 64)     // 576 threads = 9 waves; wave = one dy
#define SCALE (1.0f / 128.0f)

__global__ __launch_bounds__(NTH) void corr_kernel(
    const float* __restrict__ in1, const float* __restrict__ in2,
    float* __restrict__ out)
{
    __shared__ float lds_a[CC][NW];        // 4 KB: in1[h] row chunk
    __shared__ float lds_b[ND][CC][WPAD];  // 38 KB: in2 rows h-4..h+4, padded

    const int b   = blockIdx.x;
    const int h   = blockIdx.y;
    const int tid = threadIdx.x;
    const int dyi = tid >> 6;   // 0..8  (wave id = dy+4)
    const int g   = tid & 63;   // lane
    const int w0  = g << 2;     // 4 pixels per lane

    float acc[4][ND];
#pragma unroll
    for (int p = 0; p < 4; ++p)
#pragma unroll
        for (int d = 0; d < ND; ++d) acc[p][d] = 0.f;

    for (int c0 = 0; c0 < NC; c0 += CC) {
        // ---- stage in1 chunk: CC*64 float4 slots (threads 0..255) ----
        if (tid < CC * (NW / 4)) {
            int ci = tid >> 6;
            int j  = tid & 63;
            const float4 v = *(const float4*)
                &in1[(((size_t)b * NC + (c0 + ci)) * NH + h) * NW + (j << 2)];
            *(float4*)&lds_a[ci][j << 2] = v;
        }
        // ---- stage in2 chunk: 9 rows x CC ch x 66 float4 slots = 2376 ----
        for (int i = tid; i < ND * CC * 66; i += NTH) {
            int rc = i / 66;
            int j  = i - rc * 66;          // float4 slot within padded row
            int rr = rc >> 2;              // row 0..8 -> in2 row h+rr-4
            int ci = rc & 3;
            int hh = h + rr - 4;
            float4 v = make_float4(0.f, 0.f, 0.f, 0.f);
            if (j > 0 && j < 65 && hh >= 0 && hh < NH) {
                v = *(const float4*)
                    &in2[(((size_t)b * NC + (c0 + ci)) * NH + hh) * NW + ((j - 1) << 2)];
            }
            *(float4*)&lds_b[rr][ci][j << 2] = v;
        }
        __syncthreads();

        // ---- compute: per channel, 12-float window -> 36 FMAs ----
#pragma unroll
        for (int ci = 0; ci < CC; ++ci) {
            float4 av = *(const float4*)&lds_a[ci][w0];
            float4 b0 = *(const float4*)&lds_b[dyi][ci][w0];
            float4 b1 = *(const float4*)&lds_b[dyi][ci][w0 + 4];
            float4 b2 = *(const float4*)&lds_b[dyi][ci][w0 + 8];
            float a[4]   = {av.x, av.y, av.z, av.w};
            float bw[12] = {b0.x, b0.y, b0.z, b0.w,
                            b1.x, b1.y, b1.z, b1.w,
                            b2.x, b2.y, b2.z, b2.w};
#pragma unroll
            for (int p = 0; p < 4; ++p)
#pragma unroll
                for (int d = 0; d < ND; ++d)
                    acc[p][d] += a[p] * bw[p + d];
        }
        __syncthreads();
    }

    // ---- epilogue: 9 coalesced float4 stores per thread ----
#pragma unroll
    for (int d = 0; d < ND; ++d) {
        float4 v;
        v.x = acc[0][d] * SCALE;
        v.y = acc[1][d] * SCALE;
        v.z = acc[2][d] * SCALE;
        v.w = acc[3][d] * SCALE;
        size_t off = ((((size_t)b * (ND * ND)) + (dyi * ND + d)) * NH + h) * NW + w0;
        *(float4*)&out[off] = v;
    }
}

extern "C" void kernel_launch(void* const* d_in, const int* in_sizes, int n_in,
                              void* d_out, int out_size, void* d_ws, size_t ws_size,
                              hipStream_t stream) {
    const float* in1 = (const float*)d_in[0];
    const float* in2 = (const float*)d_in[1];
    float* out = (float*)d_out;
    dim3 grid(NB, NH);  // b on x -> XCD round-robin keeps each batch's in2 rows in one XCD's L2
    corr_kernel<<<grid, NTH, 0, stream>>>(in1, in2, out);
}

// Round 3
// 411.358 us; speedup vs baseline: 1.3952x; 1.3952x over previous
//
#include <hip/hip_runtime.h>

// FlowNetC correlation: B=8, C=128, H=128, W=256, PAD=4, MD=4, K=1, S1=S2=1
// out[b, dyi*9+dxi, h, w] = (1/128) * sum_c in1[b,c,h,w] * in2[b,c,h+dyi-4,w+dxi-4]
// (in2 zero outside bounds)
//
// R3: fully wave-independent. No LDS, no barriers, no shuffles.
// Wave = one (b, h-pair, dy): 64 lanes x 8 px = 512 px = 2 rows of W=256.
// Per channel: in1 = 2 float4 loads, in2 = 4 overlapping float4 loads giving
// bw[0..15] = in2[w0-4 .. w0+11]; 72 FMAs (8 px x 9 dx). Depth-1 prefetch.
// Edge lanes clamp addresses; the resulting garbage only feeds acc entries
// whose in2 sample is in the zero-pad region -> zeroed in the epilogue.

#define NB 8
#define NC 128
#define NH 128
#define NW 256
#define ND 9
#define CH 32768                 // NH*NW floats = channel stride
#define SCALE (1.0f / 128.0f)

__global__ __launch_bounds__(256) void corr_kernel(
    const float* __restrict__ in1, const float* __restrict__ in2,
    float* __restrict__ out)
{
    // 1152 blocks x 4 waves = 4608 waves = 8 b x 64 hp x 9 dy.
    // XCD swizzle: consecutive blockIdx round-robin XCDs, so give XCD x the
    // contiguous id range [x*576, (x+1)*576) -> each XCD owns exactly one b.
    const int bid = blockIdx.x;
    const int id  = ((bid & 7) * 144 + (bid >> 3)) * 4 + (threadIdx.x >> 6);
    const int g   = threadIdx.x & 63;

    const int dyi  = id % ND;
    const int rest = id / ND;        // 0..511
    const int hp   = rest & 63;
    const int b    = rest >> 6;

    const int r  = g >> 5;           // sub-row 0/1
    const int L  = g & 31;           // lane within row
    const int w0 = L << 3;           // 8 px per lane: w0..w0+7
    const int h  = (hp << 1) + r;    // output row (per-lane)
    const int hh = h + dyi - 4;      // in2 source row (per-lane)
    const bool valid = ((unsigned)hh < (unsigned)NH);
    const int hhc = valid ? hh : 0;  // clamped for safe addressing

    // in2 float offsets within row, clamped at image edges (values unused there)
    const int o0 = (L == 0)  ? w0       : (w0 - 4);
    const int o3 = (L == 31) ? (w0 + 4) : (w0 + 8);

    const float* aq  = in1 + (size_t)(b * NC * NH + h)   * NW + w0;
    const float* bpr = in2 + (size_t)(b * NC * NH + hhc) * NW;
    const float* b0p = bpr + o0;
    const float* b1p = bpr + w0;
    const float* b3p = bpr + o3;

    float acc[8][ND];
#pragma unroll
    for (int p = 0; p < 8; ++p)
#pragma unroll
        for (int d = 0; d < ND; ++d) acc[p][d] = 0.f;

    // prefetch channel 0
    float4 A0 = *(const float4*)(aq);
    float4 A1 = *(const float4*)(aq + 4);
    float4 B0 = *(const float4*)(b0p);
    float4 B1 = *(const float4*)(b1p);
    float4 B2 = *(const float4*)(b1p + 4);
    float4 B3 = *(const float4*)(b3p);

    for (int c = 0; c < NC - 1; ++c) {
        const float a_[8]  = {A0.x, A0.y, A0.z, A0.w, A1.x, A1.y, A1.z, A1.w};
        const float bw[16] = {B0.x, B0.y, B0.z, B0.w, B1.x, B1.y, B1.z, B1.w,
                              B2.x, B2.y, B2.z, B2.w, B3.x, B3.y, B3.z, B3.w};
        // prefetch next channel while computing this one
        aq += CH; b0p += CH; b1p += CH; b3p += CH;
        A0 = *(const float4*)(aq);
        A1 = *(const float4*)(aq + 4);
        B0 = *(const float4*)(b0p);
        B1 = *(const float4*)(b1p);
        B2 = *(const float4*)(b1p + 4);
        B3 = *(const float4*)(b3p);
#pragma unroll
        for (int p = 0; p < 8; ++p)
#pragma unroll
            for (int d = 0; d < ND; ++d)
                acc[p][d] += a_[p] * bw[p + d];
    }
    {   // tail channel (last prefetch)
        const float a_[8]  = {A0.x, A0.y, A0.z, A0.w, A1.x, A1.y, A1.z, A1.w};
        const float bw[16] = {B0.x, B0.y, B0.z, B0.w, B1.x, B1.y, B1.z, B1.w,
                              B2.x, B2.y, B2.z, B2.w, B3.x, B3.y, B3.z, B3.w};
#pragma unroll
        for (int p = 0; p < 8; ++p)
#pragma unroll
            for (int d = 0; d < ND; ++d)
                acc[p][d] += a_[p] * bw[p + d];
    }

    // epilogue: zero the entries whose in2 sample is out of bounds
    float* outp = out + ((size_t)(b * (ND * ND) + dyi * ND) * NH + h) * NW + w0;
#pragma unroll
    for (int d = 0; d < ND; ++d) {
        float v[8];
#pragma unroll
        for (int p = 0; p < 8; ++p) {
            const bool kill = (!valid) ||
                              (L == 0  && (p + d) < 4) ||    // w-sample < 0
                              (L == 31 && (p + d) > 11);     // w-sample > 255
            v[p] = kill ? 0.0f : acc[p][d] * SCALE;
        }
        float4 lo = {v[0], v[1], v[2], v[3]};
        float4 hi = {v[4], v[5], v[6], v[7]};
        *(float4*)(outp + (size_t)d * CH)     = lo;
        *(float4*)(outp + (size_t)d * CH + 4) = hi;
    }
}

extern "C" void kernel_launch(void* const* d_in, const int* in_sizes, int n_in,
                              void* d_out, int out_size, void* d_ws, size_t ws_size,
                              hipStream_t stream) {
    const float* in1 = (const float*)d_in[0];
    const float* in2 = (const float*)d_in[1];
    float* out = (float*)d_out;
    corr_kernel<<<dim3(1152), dim3(256), 0, stream>>>(in1, in2, out);
}